// Round 1
// baseline (5773.879 us; speedup 1.0000x reference)
//
#include <hip/hip_runtime.h>
#include <math.h>

// RPNHead: conv3x3(512->512)+ReLU -> cls(9)/reg(36) 1x1 -> sigmoid/box-decode
// -> per-image exact top-1000 (by f64 score, index tie-break) -> greedy NMS
// -> [8,300,5] f32 output (kept-first stable order, zero-padded).
//
// Everything score/box-relevant is computed in fp64 so that top-k ordering and
// NMS decisions match a float64 numpy reference exactly (score spacing ~1e-5
// >> f64 noise ~1e-16; fp32 would risk rank swaps -> absmax ~1000).

#define BS 8
#define CIN 512
#define COUT 512
#define FH 64
#define FW 64
#define NA 9
#define NPIX (FH*FW)          // 4096
#define NANCH (NPIX*NA)       // 36864
#define NPAD 65536
#define KPRE 1000
#define KPOST 300

// ---- workspace layout (bytes) ----
#define OFF_X      0ull                                   // 8*512*4096 f64 = 134217728
#define OFF_SCORES (OFF_X + 134217728ull)                 // 8*36864 f64    = 2359296
#define OFF_BOXES  (OFF_SCORES + 2359296ull)              // 8*36864*4 f64  = 9437184
#define OFF_KEYS   (OFF_BOXES + 9437184ull)               // 8*65536 u64    = 4194304
#define OFF_BUF1   (OFF_KEYS + 4194304ull)                // 8*16*1024 u64  = 1048576
#define OFF_BUF2   (OFF_BUF1 + 1048576ull)                // 8*4*1024 u64   = 262144
#define OFF_SEL    (OFF_BUF2 + 262144ull)                 // 8*1024 i32     = 32768
#define OFF_KEEP   (OFF_SEL + 32768ull)                   // 8*1024 i32     = 32768
#define WS_NEEDED  (OFF_KEEP + 32768ull)

// ---------------- conv 3x3 + bias + relu, f64 accumulate ----------------
// grid (4 ocb, 64 h, 8 b), block (16,16). Block tile: 128 oc x 64 pix (one row).
// Thread: 8 oc x 4 pix register blocking, f64 acc.
__global__ __launch_bounds__(256) void conv_kernel(
    const float* __restrict__ fm, const float* __restrict__ W,
    const float* __restrict__ bias, double* __restrict__ x) {
  __shared__ double sW[36 * 128];    // [(c*9+t)*128 + o]
  __shared__ double sIn[4 * 3 * 72]; // [(c*3+r)*72 + col], col = gx+1 (0..65)
  const int ocb = blockIdx.x, h = blockIdx.y, b = blockIdx.z;
  const int tx = threadIdx.x, ty = threadIdx.y;
  const int tid = ty * 16 + tx;
  const int oc0 = ocb * 128;

  double acc[8][4];
#pragma unroll
  for (int j = 0; j < 8; ++j)
#pragma unroll
    for (int i = 0; i < 4; ++i) acc[j][i] = 0.0;

  for (int cc = 0; cc < CIN; cc += 4) {
    // stage weights: 128 oc x 4 cin x 9 taps
    for (int li = tid; li < 4608; li += 256) {
      int o = li & 127, ct = li >> 7;       // ct = c*9+t
      int c = ct / 9, t = ct % 9;
      sW[li] = (double)W[((long)(oc0 + o) * CIN + cc + c) * 9 + t];
    }
    // stage input patch: 4 cin x 3 rows x 66 cols (zero-padded)
    for (int li = tid; li < 792; li += 256) {
      int c = li / 198, rem = li % 198, r = rem / 66, col = rem % 66;
      int gy = h + r - 1, gx = col - 1;
      float v = 0.f;
      if (gy >= 0 && gy < FH && gx >= 0 && gx < FW)
        v = fm[((long)(b * CIN + cc + c) * FH + gy) * FW + gx];
      sIn[(c * 3 + r) * 72 + col] = (double)v;
    }
    __syncthreads();
#pragma unroll
    for (int c = 0; c < 4; ++c) {
#pragma unroll
      for (int t = 0; t < 9; ++t) {
        const int dy = t / 3, dx = t % 3;
        double iv[4];
#pragma unroll
        for (int i = 0; i < 4; ++i)
          iv[i] = sIn[(c * 3 + dy) * 72 + tx + 16 * i + dx];
#pragma unroll
        for (int j = 0; j < 8; ++j) {
          double wv = sW[(c * 9 + t) * 128 + ty * 8 + j];
#pragma unroll
          for (int i = 0; i < 4; ++i) acc[j][i] += wv * iv[i];
        }
      }
    }
    __syncthreads();
  }

#pragma unroll
  for (int j = 0; j < 8; ++j) {
    const int oc = oc0 + ty * 8 + j;
    const double bv = (double)bias[oc];
#pragma unroll
    for (int i = 0; i < 4; ++i) {
      double v = acc[j][i] + bv;
      v = v > 0.0 ? v : 0.0;
      x[((long)(b * COUT) + oc) * NPIX + h * FW + tx + 16 * i] = v;
    }
  }
}

// ---------------- heads: 45 logits/pixel -> scores, boxes, sort keys ----------
// grid 512 (= 8 img * 64 pixel-tiles of 64), block (64,4).
__global__ __launch_bounds__(256) void heads_kernel(
    const double* __restrict__ x, const float* __restrict__ cls_w,
    const float* __restrict__ cls_b, const float* __restrict__ reg_w,
    const float* __restrict__ reg_b, const int* __restrict__ img_h,
    const int* __restrict__ img_w, double* __restrict__ scores,
    double* __restrict__ boxes, unsigned long long* __restrict__ keys) {
  __shared__ double sx[4096];  // [ci][px]
  __shared__ double swl[2880]; // union: weights [45][64] per chunk, then logits [45][64]
  const int b = blockIdx.x >> 6;
  const int ptile = blockIdx.x & 63;
  const int tx = threadIdx.x, ty = threadIdx.y;
  const int tid = ty * 64 + tx;

  double acc[12];
#pragma unroll
  for (int j = 0; j < 12; ++j) acc[j] = 0.0;

  for (int cc = 0; cc < CIN; cc += 64) {
    for (int li = tid; li < 4096; li += 256) {
      int ci = li >> 6, px = li & 63;
      sx[li] = x[((long)b * CIN + cc + ci) * NPIX + ptile * 64 + px];
    }
    for (int li = tid; li < 2880; li += 256) {
      int o = li >> 6, ci = li & 63;
      float wv = (o < 9) ? cls_w[o * CIN + cc + ci] : reg_w[(o - 9) * CIN + cc + ci];
      swl[li] = (double)wv;
    }
    __syncthreads();
#pragma unroll 4
    for (int ci = 0; ci < 64; ++ci) {
      double xv = sx[ci * 64 + tx];
#pragma unroll
      for (int j = 0; j < 12; ++j) {
        int o = ty + 4 * j;
        if (o < 45) acc[j] += swl[o * 64 + ci] * xv;
      }
    }
    __syncthreads();
  }

  // bias, write logits to LDS (reuse swl)
#pragma unroll
  for (int j = 0; j < 12; ++j) {
    int o = ty + 4 * j;
    if (o < 45) {
      double bv = (o < 9) ? (double)cls_b[o] : (double)reg_b[o - 9];
      swl[o * 64 + tx] = acc[j] + bv;
    }
  }
  __syncthreads();

  const double ih = (double)img_h[0], iw = (double)img_w[0];
  const double sth = ih / (double)FH, stw = iw / (double)FW;
  const double ratios[3] = {0.5, 1.0, 2.0};
  const double sizes[3] = {128.0, 256.0, 512.0};

  for (int it = tid; it < 576; it += 256) {
    int px = it / 9, a = it % 9;
    int p = ptile * 64 + px;
    int hh = p >> 6, ww = p & 63;
    double z = swl[a * 64 + px];
    double score = 1.0 / (1.0 + exp(-z));
    double d0 = swl[(9 + a * 4 + 0) * 64 + px];
    double d1 = swl[(9 + a * 4 + 1) * 64 + px];
    double d2 = swl[(9 + a * 4 + 2) * 64 + px];
    double d3 = swl[(9 + a * 4 + 3) * 64 + px];
    double ratio = ratios[a / 3], size = sizes[a % 3];
    double hr = sqrt(ratio), wr = 1.0 / hr;
    double wsz = wr * size, hsz = hr * size;
    double sxc = (double)ww * stw, syc = (double)hh * sth;
    double ax0 = sxc - wsz * 0.5, ax1 = sxc + wsz * 0.5;
    double ay0 = syc - hsz * 0.5, ay1 = syc + hsz * 0.5;
    double aw = ax1 - ax0, ah = ay1 - ay0;
    double acx = ax0 + 0.5 * aw, acy = ay0 + 0.5 * ah;
    double pcx = d0 * aw + acx, pcy = d1 * ah + acy;
    double pw = exp(d2) * aw, ph = exp(d3) * ah;
    double bx0 = pcx - 0.5 * pw, by0 = pcy - 0.5 * ph;
    double bx1 = pcx + 0.5 * pw, by1 = pcy + 0.5 * ph;
    bx0 = fmin(fmax(bx0, 0.0), iw); bx1 = fmin(fmax(bx1, 0.0), iw);
    by0 = fmin(fmax(by0, 0.0), ih); by1 = fmin(fmax(by1, 0.0), ih);
    long n = (long)p * 9 + a;
    long base = (long)b * NANCH + n;
    boxes[base * 4 + 0] = bx0; boxes[base * 4 + 1] = by0;
    boxes[base * 4 + 2] = bx1; boxes[base * 4 + 3] = by1;
    scores[base] = score;
    // key: ascending-sortable, primary = descending score (48-bit truncated
    // bits of positive double), secondary = ascending index. n = ikey & 0xFFFF.
    unsigned long long bits = (unsigned long long)__double_as_longlong(score);
    keys[(long)b * NPAD + n] =
        ~((bits & 0xFFFFFFFFFFFF0000ull) | (0xFFFFull - (unsigned long long)n));
  }
}

// ---------------- bitonic sort of 4096 u64 in LDS (ascending) ----------------
__device__ inline void bitonic4096(unsigned long long* s, int tid) {
  for (int k = 2; k <= 4096; k <<= 1) {
    for (int j = k >> 1; j > 0; j >>= 1) {
#pragma unroll 2
      for (int t = tid; t < 2048; t += 1024) {
        int i = ((t & ~(j - 1)) << 1) | (t & (j - 1));
        int p = i | j;
        bool up = ((i & k) == 0);
        unsigned long long a = s[i], c = s[p];
        if ((a > c) == up) { s[i] = c; s[p] = a; }
      }
      __syncthreads();
    }
  }
}

// sorts a 4096 chunk, writes its smallest (best) 1024 keys.
__global__ __launch_bounds__(1024) void sort_topk_kernel(
    const unsigned long long* __restrict__ in, unsigned long long* __restrict__ out,
    long in_stride, long out_stride) {
  __shared__ unsigned long long s[4096];
  const int b = blockIdx.y, q = blockIdx.x, tid = threadIdx.x;
  const unsigned long long* ip = in + (long)b * in_stride + (long)q * 4096;
#pragma unroll 4
  for (int l = tid; l < 4096; l += 1024) s[l] = ip[l];
  __syncthreads();
  bitonic4096(s, tid);
  unsigned long long* op = out + (long)b * out_stride + (long)q * 1024;
  op[tid] = s[tid];
}

// final: sort 4096 candidates, decode top-1000 anchor indices.
__global__ __launch_bounds__(1024) void sort_final_kernel(
    const unsigned long long* __restrict__ in, int* __restrict__ sel) {
  __shared__ unsigned long long s[4096];
  const int b = blockIdx.x, tid = threadIdx.x;
  const unsigned long long* ip = in + (long)b * 4096;
#pragma unroll 4
  for (int l = tid; l < 4096; l += 1024) s[l] = ip[l];
  __syncthreads();
  bitonic4096(s, tid);
  if (tid < KPRE) sel[b * 1024 + tid] = (int)(s[tid] & 0xFFFFull);
}

// ---------------- greedy sequential NMS, f64, one block per image ------------
__global__ __launch_bounds__(256) void nms_kernel(
    const double* __restrict__ boxes, const int* __restrict__ sel,
    int* __restrict__ keep) {
  __shared__ double X0[KPRE], Y0[KPRE], X1[KPRE], Y1[KPRE], AR[KPRE];
  __shared__ int KP[KPRE];
  const int b = blockIdx.x, tid = threadIdx.x;
  for (int r = tid; r < KPRE; r += 256) {
    int n = sel[b * 1024 + r];
    const double* bp = boxes + ((long)b * NANCH + n) * 4;
    double x0 = bp[0], y0 = bp[1], x1 = bp[2], y1 = bp[3];
    X0[r] = x0; Y0[r] = y0; X1[r] = x1; Y1[r] = y1;
    AR[r] = (x1 - x0) * (y1 - y0);
    KP[r] = 1;
  }
  __syncthreads();
  for (int i = 0; i < KPRE - 1; ++i) {
    if (KP[i]) {
      double xi0 = X0[i], yi0 = Y0[i], xi1 = X1[i], yi1 = Y1[i], ai = AR[i];
      for (int j = i + 1 + tid; j < KPRE; j += 256) {
        double lx = fmax(xi0, X0[j]), ly = fmax(yi0, Y0[j]);
        double rx = fmin(xi1, X1[j]), ry = fmin(yi1, Y1[j]);
        double w = rx - lx; w = fmax(w, 0.0);
        double h = ry - ly; h = fmax(h, 0.0);
        double inter = w * h;
        double iou = inter / (ai + AR[j] - inter + 1e-9);
        if (iou > 0.7) KP[j] = 0;
      }
    }
    __syncthreads();
  }
  for (int r = tid; r < KPRE; r += 256) keep[b * 1024 + r] = KP[r];
}

// ---------------- output: kept-first stable order, zero pad ------------------
__global__ __launch_bounds__(1024) void out_kernel(
    const double* __restrict__ boxes, const double* __restrict__ scores,
    const int* __restrict__ sel, const int* __restrict__ keep,
    float* __restrict__ out) {
  const int b = blockIdx.x, tid = threadIdx.x;
  int kv = (tid < KPRE) ? keep[b * 1024 + tid] : 0;
  unsigned long long m = __ballot(kv != 0);
  int lane = tid & 63, wid = tid >> 6;
  __shared__ int wcnt[16], woff[16], tot;
  if (lane == 0) wcnt[wid] = __popcll(m);
  __syncthreads();
  if (tid == 0) {
    int s = 0;
    for (int w2 = 0; w2 < 16; ++w2) { woff[w2] = s; s += wcnt[w2]; }
    tot = s;
  }
  __syncthreads();
  int before = __popcll(m & ((1ull << lane) - 1ull));
  int pref = woff[wid] + before;  // kept strictly before tid
  if (tid < KPRE) {
    int pos = kv ? pref : (tot + (tid - pref));
    if (pos < KPOST) {
      float* o = out + ((long)b * KPOST + pos) * 5;
      if (kv) {
        int n = sel[b * 1024 + tid];
        const double* bp = boxes + ((long)b * NANCH + n) * 4;
        o[0] = (float)bp[0]; o[1] = (float)bp[1];
        o[2] = (float)bp[2]; o[3] = (float)bp[3];
        o[4] = (float)scores[(long)b * NANCH + n];
      } else {
        o[0] = 0.f; o[1] = 0.f; o[2] = 0.f; o[3] = 0.f; o[4] = 0.f;
      }
    }
  }
}

extern "C" void kernel_launch(void* const* d_in, const int* in_sizes, int n_in,
                              void* d_out, int out_size, void* d_ws, size_t ws_size,
                              hipStream_t stream) {
  const float* fm     = (const float*)d_in[0];
  const float* base_w = (const float*)d_in[1];
  const float* base_b = (const float*)d_in[2];
  const float* cls_w  = (const float*)d_in[3];
  const float* cls_b  = (const float*)d_in[4];
  const float* reg_w  = (const float*)d_in[5];
  const float* reg_b  = (const float*)d_in[6];
  const int* img_h    = (const int*)d_in[7];
  const int* img_w    = (const int*)d_in[8];
  float* out          = (float*)d_out;

  if (ws_size < WS_NEEDED) return;  // visible failure rather than corruption

  char* ws = (char*)d_ws;
  double* x                 = (double*)(ws + OFF_X);
  double* scores            = (double*)(ws + OFF_SCORES);
  double* boxes             = (double*)(ws + OFF_BOXES);
  unsigned long long* keys  = (unsigned long long*)(ws + OFF_KEYS);
  unsigned long long* buf1  = (unsigned long long*)(ws + OFF_BUF1);
  unsigned long long* buf2  = (unsigned long long*)(ws + OFF_BUF2);
  int* sel                  = (int*)(ws + OFF_SEL);
  int* keep                 = (int*)(ws + OFF_KEEP);

  // pad keys (anchors 36864..65535) and buf1 (chunks 9..15) with worst key
  hipMemsetAsync(ws + OFF_KEYS, 0xFF, 4194304ull + 1048576ull, stream);

  conv_kernel<<<dim3(4, 64, 8), dim3(16, 16), 0, stream>>>(fm, base_w, base_b, x);
  heads_kernel<<<dim3(512), dim3(64, 4), 0, stream>>>(
      x, cls_w, cls_b, reg_w, reg_b, img_h, img_w, scores, boxes, keys);
  // exact top-1000: chunk sorts (top-1024 each) -> 2-level merge
  sort_topk_kernel<<<dim3(9, 8), dim3(1024), 0, stream>>>(keys, buf1, 65536, 16384);
  sort_topk_kernel<<<dim3(4, 8), dim3(1024), 0, stream>>>(buf1, buf2, 16384, 4096);
  sort_final_kernel<<<dim3(8), dim3(1024), 0, stream>>>(buf2, sel);
  nms_kernel<<<dim3(8), dim3(256), 0, stream>>>(boxes, sel, keep);
  out_kernel<<<dim3(8), dim3(1024), 0, stream>>>(boxes, scores, sel, keep, out);
}

// Round 4
// 3930.537 us; speedup vs baseline: 1.4690x; 1.4690x over previous
//
#include <hip/hip_runtime.h>
#include <math.h>

// RPNHead: conv3x3(512->512)+ReLU -> cls(9)/reg(36) 1x1 -> sigmoid/box-decode
// -> per-image exact top-1000 (by f64 score, index tie-break) -> greedy NMS
// -> [8,300,5] f32 output (kept-first stable order, zero-padded).
//
// Score/box pipeline in fp64 so top-k ordering and NMS decisions match a
// float64 numpy reference exactly (adjacent-score spacing ~5e-5..5e-8 >> f64
// noise ~1e-16; f32 would swap ranks -> wrong rows -> absmax ~1000).
//
// R2: conv as implicit-GEMM on v_mfma_f64_16x16x4_f64 (matrix pipe).
// R3: fixed weight-staging double-offset bug. Still failed -> remaining
//     suspect is the f64 MFMA lane mapping itself (never HW-verified on
//     gfx950; the dtype-independence sweep excluded f64).
// R4: layout-agnostic epilogue. A probe MFMA computes D[i][j]=i+16j with
//     exact integers; each (lane,reg) decodes its true (row,col) and the
//     epilogue scatters accordingly. Correct under any C/D layout variant,
//     operand-role swap, or A/B transpose (any mapping that contracts fed-k
//     against fed-k). If the assumed layout was right, this decodes to the
//     identical indices as R3 (no-op).

typedef double f64x4 __attribute__((ext_vector_type(4)));

#define BS 8
#define CIN 512
#define COUT 512
#define FH 64
#define FW 64
#define NA 9
#define NPIX (FH*FW)          // 4096
#define NANCH (NPIX*NA)       // 36864
#define NPAD 65536
#define KPRE 1000
#define KPOST 300

// ---- workspace layout (bytes) ----
#define OFF_X      0ull                                   // 8*512*4096 f64 = 134217728
#define OFF_SCORES (OFF_X + 134217728ull)                 // 8*36864 f64    = 2359296
#define OFF_BOXES  (OFF_SCORES + 2359296ull)              // 8*36864*4 f64  = 9437184
#define OFF_KEYS   (OFF_BOXES + 9437184ull)               // 8*65536 u64    = 4194304
#define OFF_BUF1   (OFF_KEYS + 4194304ull)                // 8*16*1024 u64  = 1048576
#define OFF_BUF2   (OFF_BUF1 + 1048576ull)                // 8*4*1024 u64   = 262144
#define OFF_SEL    (OFF_BUF2 + 262144ull)                 // 8*1024 i32     = 32768
#define OFF_KEEP   (OFF_SEL + 32768ull)                   // 8*1024 i32     = 32768
#define WS_NEEDED  (OFF_KEEP + 32768ull)

// ---------------- conv 3x3 + bias + relu, f64 MFMA implicit GEMM -------------
// grid (8 ocb, 32 rowpair, 8 b), block 256 = 4 waves.
// Block tile: 64 oc x 128 pix (2 image rows). Wave tile: 32 oc x 64 pix
// = 2x4 MFMA 16x16 tiles. K-chunk = 4 cin x 9 taps = 36, K total 4608.
// Feed convention (CDNA2 dgemm reference): A[m][k]: m=lane%16, k=lane/16.
// B[k][n]: k=lane/16, n=lane%16. D mapping: decoded at runtime by probe.
__global__ __launch_bounds__(256) void conv_mfma_kernel(
    const float* __restrict__ fm, const float* __restrict__ W,
    const float* __restrict__ bias, double* __restrict__ x) {
  __shared__ double sW[36 * 64];      // [k][oc_local]
  __shared__ double sIn[4 * 4 * 72];  // [c][r][col], col = gx+1 (0..65 used)
  const int ocb = blockIdx.x, rp = blockIdx.y, b = blockIdx.z;
  const int h0 = rp * 2;
  const int oc0 = ocb * 64;
  const int tid = threadIdx.x;
  const int wid = tid >> 6, l = tid & 63;
  const int q = l >> 4, r16 = l & 15;
  const int wm = wid >> 1, wn = wid & 1;   // wave grid 2(M) x 2(N)

  // ---- C/D layout probe: construct D[i][j] = i + 16*j with exact ints.
  // A[i][0]=i, A[i][1]=1, rest 0; B[0][j]=1, B[1][j]=16*j, rest 0.
  // Then (lane,reg) holding value val sits at true row=val%16, col=val/16.
  int prow[4], pcol[4];
  {
    f64x4 probe = {0.0, 0.0, 0.0, 0.0};
    double pa = (q == 0) ? (double)r16 : ((q == 1) ? 1.0 : 0.0);
    double pb = (q == 0) ? 1.0 : ((q == 1) ? (double)(16 * r16) : 0.0);
    probe = __builtin_amdgcn_mfma_f64_16x16x4f64(pa, pb, probe, 0, 0, 0);
#pragma unroll
    for (int v = 0; v < 4; ++v) {
      int val = (int)(probe[v] + 0.5);
      prow[v] = val & 15;
      pcol[v] = (val >> 4) & 15;
    }
  }

  f64x4 acc[2][4];
#pragma unroll
  for (int tm = 0; tm < 2; ++tm)
#pragma unroll
    for (int tn = 0; tn < 4; ++tn)
#pragma unroll
      for (int v = 0; v < 4; ++v) acc[tm][tn][v] = 0.0;

  // per-lane LDS fragment base pointers
  const double* sWp  = &sW[q * 64 + wm * 32 + r16];   // + k0*64 + tm*16
  const double* sInp = &sIn[wn * 72 + r16];           // + c*288 + dy*72 + dx + tn*16

  // weight staging map: thread tid -> oc o = tid/4, k-segment seg = tid%4 (9 ks)
  // sW[k][o] = W[(oc0+o)*4608 + cc*9 + k]  (k = c*9+t matches W's (cin)*9+tap
  // flattening; k already encodes wseg*9 -- base must NOT).
  const int wo = tid >> 2, wseg = tid & 3;
  const float* wsrc = W + (size_t)(oc0 + wo) * 4608;

  for (int cc = 0; cc < CIN; cc += 4) {
#pragma unroll
    for (int j = 0; j < 9; ++j) {
      int k = wseg * 9 + j;
      sW[k * 64 + wo] = (double)wsrc[cc * 9 + k];
    }
    // stage input patch: 4 cin x 4 rows (h0-1..h0+2) x 66 cols, zero-padded
    for (int i = tid; i < 1056; i += 256) {
      int c = i / 264, rem = i % 264, r = rem / 66, col = rem % 66;
      int gy = h0 - 1 + r, gx = col - 1;
      float v = 0.f;
      if (gy >= 0 && gy < FH && gx >= 0 && gx < FW)
        v = fm[((size_t)(b * CIN + cc + c) * FH + gy) * FW + gx];
      sIn[(c * 4 + r) * 72 + col] = (double)v;
    }
    __syncthreads();

#pragma unroll
    for (int k0s = 0; k0s < 9; ++k0s) {
      const int k0 = k0s * 4;
      // per-lane k for the B (im2col) fragment
      int k = k0 + q;
      int c = k / 9;
      int t = k - 9 * c;
      int dy = t / 3;
      int dx = t - 3 * dy;
      int off = c * 288 + dy * 72 + dx;
      double a0 = sWp[k0 * 64];
      double a1 = sWp[k0 * 64 + 16];
      double b0 = sInp[off];
      double b1 = sInp[off + 16];
      double b2 = sInp[off + 32];
      double b3 = sInp[off + 48];
      acc[0][0] = __builtin_amdgcn_mfma_f64_16x16x4f64(a0, b0, acc[0][0], 0, 0, 0);
      acc[0][1] = __builtin_amdgcn_mfma_f64_16x16x4f64(a0, b1, acc[0][1], 0, 0, 0);
      acc[0][2] = __builtin_amdgcn_mfma_f64_16x16x4f64(a0, b2, acc[0][2], 0, 0, 0);
      acc[0][3] = __builtin_amdgcn_mfma_f64_16x16x4f64(a0, b3, acc[0][3], 0, 0, 0);
      acc[1][0] = __builtin_amdgcn_mfma_f64_16x16x4f64(a1, b0, acc[1][0], 0, 0, 0);
      acc[1][1] = __builtin_amdgcn_mfma_f64_16x16x4f64(a1, b1, acc[1][1], 0, 0, 0);
      acc[1][2] = __builtin_amdgcn_mfma_f64_16x16x4f64(a1, b2, acc[1][2], 0, 0, 0);
      acc[1][3] = __builtin_amdgcn_mfma_f64_16x16x4f64(a1, b3, acc[1][3], 0, 0, 0);
    }
    __syncthreads();
  }

  // epilogue: probe-decoded D mapping; bias + relu
#pragma unroll
  for (int tm = 0; tm < 2; ++tm) {
#pragma unroll
    for (int v = 0; v < 4; ++v) {
      const int oc = oc0 + wm * 32 + tm * 16 + prow[v];
      const double bv = (double)bias[oc];
      const int h = h0 + wn;
#pragma unroll
      for (int tn = 0; tn < 4; ++tn) {
        const int w = tn * 16 + pcol[v];
        double val = acc[tm][tn][v] + bv;
        val = val > 0.0 ? val : 0.0;
        x[(size_t)(b * COUT + oc) * NPIX + h * FW + w] = val;
      }
    }
  }
}

// ---------------- heads: 45 logits/pixel -> scores, boxes, sort keys ----------
// grid 512 (= 8 img * 64 pixel-tiles of 64), block (64,4).
__global__ __launch_bounds__(256) void heads_kernel(
    const double* __restrict__ x, const float* __restrict__ cls_w,
    const float* __restrict__ cls_b, const float* __restrict__ reg_w,
    const float* __restrict__ reg_b, const int* __restrict__ img_h,
    const int* __restrict__ img_w, double* __restrict__ scores,
    double* __restrict__ boxes, unsigned long long* __restrict__ keys) {
  __shared__ double sx[4096];  // [ci][px]
  __shared__ double swl[2880]; // union: weights [45][64] per chunk, then logits [45][64]
  const int b = blockIdx.x >> 6;
  const int ptile = blockIdx.x & 63;
  const int tx = threadIdx.x, ty = threadIdx.y;
  const int tid = ty * 64 + tx;

  double acc[12];
#pragma unroll
  for (int j = 0; j < 12; ++j) acc[j] = 0.0;

  for (int cc = 0; cc < CIN; cc += 64) {
    for (int li = tid; li < 4096; li += 256) {
      int ci = li >> 6, px = li & 63;
      sx[li] = x[((long)b * CIN + cc + ci) * NPIX + ptile * 64 + px];
    }
    for (int li = tid; li < 2880; li += 256) {
      int o = li >> 6, ci = li & 63;
      float wv = (o < 9) ? cls_w[o * CIN + cc + ci] : reg_w[(o - 9) * CIN + cc + ci];
      swl[li] = (double)wv;
    }
    __syncthreads();
#pragma unroll 4
    for (int ci = 0; ci < 64; ++ci) {
      double xv = sx[ci * 64 + tx];
#pragma unroll
      for (int j = 0; j < 12; ++j) {
        int o = ty + 4 * j;
        if (o < 45) acc[j] += swl[o * 64 + ci] * xv;
      }
    }
    __syncthreads();
  }

  // bias, write logits to LDS (reuse swl)
#pragma unroll
  for (int j = 0; j < 12; ++j) {
    int o = ty + 4 * j;
    if (o < 45) {
      double bv = (o < 9) ? (double)cls_b[o] : (double)reg_b[o - 9];
      swl[o * 64 + tx] = acc[j] + bv;
    }
  }
  __syncthreads();

  const double ih = (double)img_h[0], iw = (double)img_w[0];
  const double sth = ih / (double)FH, stw = iw / (double)FW;
  const double ratios[3] = {0.5, 1.0, 2.0};
  const double sizes[3] = {128.0, 256.0, 512.0};

  for (int it = tid; it < 576; it += 256) {
    int px = it / 9, a = it % 9;
    int p = ptile * 64 + px;
    int hh = p >> 6, ww = p & 63;
    double z = swl[a * 64 + px];
    double score = 1.0 / (1.0 + exp(-z));
    double d0 = swl[(9 + a * 4 + 0) * 64 + px];
    double d1 = swl[(9 + a * 4 + 1) * 64 + px];
    double d2 = swl[(9 + a * 4 + 2) * 64 + px];
    double d3 = swl[(9 + a * 4 + 3) * 64 + px];
    double ratio = ratios[a / 3], size = sizes[a % 3];
    double hr = sqrt(ratio), wr = 1.0 / hr;
    double wsz = wr * size, hsz = hr * size;
    double sxc = (double)ww * stw, syc = (double)hh * sth;
    double ax0 = sxc - wsz * 0.5, ax1 = sxc + wsz * 0.5;
    double ay0 = syc - hsz * 0.5, ay1 = syc + hsz * 0.5;
    double aw = ax1 - ax0, ah = ay1 - ay0;
    double acx = ax0 + 0.5 * aw, acy = ay0 + 0.5 * ah;
    double pcx = d0 * aw + acx, pcy = d1 * ah + acy;
    double pw = exp(d2) * aw, ph = exp(d3) * ah;
    double bx0 = pcx - 0.5 * pw, by0 = pcy - 0.5 * ph;
    double bx1 = pcx + 0.5 * pw, by1 = pcy + 0.5 * ph;
    bx0 = fmin(fmax(bx0, 0.0), iw); bx1 = fmin(fmax(bx1, 0.0), iw);
    by0 = fmin(fmax(by0, 0.0), ih); by1 = fmin(fmax(by1, 0.0), ih);
    long n = (long)p * 9 + a;
    long base = (long)b * NANCH + n;
    boxes[base * 4 + 0] = bx0; boxes[base * 4 + 1] = by0;
    boxes[base * 4 + 2] = bx1; boxes[base * 4 + 3] = by1;
    scores[base] = score;
    // key: ascending-sortable, primary = descending score (48-bit truncated
    // bits of positive double), secondary = ascending index. n = ikey & 0xFFFF.
    unsigned long long bits = (unsigned long long)__double_as_longlong(score);
    keys[(long)b * NPAD + n] =
        ~((bits & 0xFFFFFFFFFFFF0000ull) | (0xFFFFull - (unsigned long long)n));
  }
}

// ---------------- bitonic sort of 4096 u64 in LDS (ascending) ----------------
__device__ inline void bitonic4096(unsigned long long* s, int tid) {
  for (int k = 2; k <= 4096; k <<= 1) {
    for (int j = k >> 1; j > 0; j >>= 1) {
#pragma unroll 2
      for (int t = tid; t < 2048; t += 1024) {
        int i = ((t & ~(j - 1)) << 1) | (t & (j - 1));
        int p = i | j;
        bool up = ((i & k) == 0);
        unsigned long long a = s[i], c = s[p];
        if ((a > c) == up) { s[i] = c; s[p] = a; }
      }
      __syncthreads();
    }
  }
}

// sorts a 4096 chunk, writes its smallest (best) 1024 keys.
__global__ __launch_bounds__(1024) void sort_topk_kernel(
    const unsigned long long* __restrict__ in, unsigned long long* __restrict__ out,
    long in_stride, long out_stride) {
  __shared__ unsigned long long s[4096];
  const int b = blockIdx.y, q = blockIdx.x, tid = threadIdx.x;
  const unsigned long long* ip = in + (long)b * in_stride + (long)q * 4096;
#pragma unroll 4
  for (int l = tid; l < 4096; l += 1024) s[l] = ip[l];
  __syncthreads();
  bitonic4096(s, tid);
  unsigned long long* op = out + (long)b * out_stride + (long)q * 1024;
  op[tid] = s[tid];
}

// final: sort 4096 candidates, decode top-1000 anchor indices.
__global__ __launch_bounds__(1024) void sort_final_kernel(
    const unsigned long long* __restrict__ in, int* __restrict__ sel) {
  __shared__ unsigned long long s[4096];
  const int b = blockIdx.x, tid = threadIdx.x;
  const unsigned long long* ip = in + (long)b * 4096;
#pragma unroll 4
  for (int l = tid; l < 4096; l += 1024) s[l] = ip[l];
  __syncthreads();
  bitonic4096(s, tid);
  if (tid < KPRE) sel[b * 1024 + tid] = (int)(s[tid] & 0xFFFFull);
}

// ---------------- greedy sequential NMS, f64, one block per image ------------
__global__ __launch_bounds__(256) void nms_kernel(
    const double* __restrict__ boxes, const int* __restrict__ sel,
    int* __restrict__ keep) {
  __shared__ double X0[KPRE], Y0[KPRE], X1[KPRE], Y1[KPRE], AR[KPRE];
  __shared__ int KP[KPRE];
  const int b = blockIdx.x, tid = threadIdx.x;
  for (int r = tid; r < KPRE; r += 256) {
    int n = sel[b * 1024 + r];
    const double* bp = boxes + ((long)b * NANCH + n) * 4;
    double x0 = bp[0], y0 = bp[1], x1 = bp[2], y1 = bp[3];
    X0[r] = x0; Y0[r] = y0; X1[r] = x1; Y1[r] = y1;
    AR[r] = (x1 - x0) * (y1 - y0);
    KP[r] = 1;
  }
  __syncthreads();
  for (int i = 0; i < KPRE - 1; ++i) {
    if (KP[i]) {
      double xi0 = X0[i], yi0 = Y0[i], xi1 = X1[i], yi1 = Y1[i], ai = AR[i];
      for (int j = i + 1 + tid; j < KPRE; j += 256) {
        double lx = fmax(xi0, X0[j]), ly = fmax(yi0, Y0[j]);
        double rx = fmin(xi1, X1[j]), ry = fmin(yi1, Y1[j]);
        double w = rx - lx; w = fmax(w, 0.0);
        double h = ry - ly; h = fmax(h, 0.0);
        double inter = w * h;
        double iou = inter / (ai + AR[j] - inter + 1e-9);
        if (iou > 0.7) KP[j] = 0;
      }
    }
    __syncthreads();
  }
  for (int r = tid; r < KPRE; r += 256) keep[b * 1024 + r] = KP[r];
}

// ---------------- output: kept-first stable order, zero pad ------------------
__global__ __launch_bounds__(1024) void out_kernel(
    const double* __restrict__ boxes, const double* __restrict__ scores,
    const int* __restrict__ sel, const int* __restrict__ keep,
    float* __restrict__ out) {
  const int b = blockIdx.x, tid = threadIdx.x;
  int kv = (tid < KPRE) ? keep[b * 1024 + tid] : 0;
  unsigned long long m = __ballot(kv != 0);
  int lane = tid & 63, wid = tid >> 6;
  __shared__ int wcnt[16], woff[16], tot;
  if (lane == 0) wcnt[wid] = __popcll(m);
  __syncthreads();
  if (tid == 0) {
    int s = 0;
    for (int w2 = 0; w2 < 16; ++w2) { woff[w2] = s; s += wcnt[w2]; }
    tot = s;
  }
  __syncthreads();
  int before = __popcll(m & ((1ull << lane) - 1ull));
  int pref = woff[wid] + before;  // kept strictly before tid
  if (tid < KPRE) {
    int pos = kv ? pref : (tot + (tid - pref));
    if (pos < KPOST) {
      float* o = out + ((long)b * KPOST + pos) * 5;
      if (kv) {
        int n = sel[b * 1024 + tid];
        const double* bp = boxes + ((long)b * NANCH + n) * 4;
        o[0] = (float)bp[0]; o[1] = (float)bp[1];
        o[2] = (float)bp[2]; o[3] = (float)bp[3];
        o[4] = (float)scores[(long)b * NANCH + n];
      } else {
        o[0] = 0.f; o[1] = 0.f; o[2] = 0.f; o[3] = 0.f; o[4] = 0.f;
      }
    }
  }
}

extern "C" void kernel_launch(void* const* d_in, const int* in_sizes, int n_in,
                              void* d_out, int out_size, void* d_ws, size_t ws_size,
                              hipStream_t stream) {
  const float* fm     = (const float*)d_in[0];
  const float* base_w = (const float*)d_in[1];
  const float* base_b = (const float*)d_in[2];
  const float* cls_w  = (const float*)d_in[3];
  const float* cls_b  = (const float*)d_in[4];
  const float* reg_w  = (const float*)d_in[5];
  const float* reg_b  = (const float*)d_in[6];
  const int* img_h    = (const int*)d_in[7];
  const int* img_w    = (const int*)d_in[8];
  float* out          = (float*)d_out;

  if (ws_size < WS_NEEDED) return;  // visible failure rather than corruption

  char* ws = (char*)d_ws;
  double* x                 = (double*)(ws + OFF_X);
  double* scores            = (double*)(ws + OFF_SCORES);
  double* boxes             = (double*)(ws + OFF_BOXES);
  unsigned long long* keys  = (unsigned long long*)(ws + OFF_KEYS);
  unsigned long long* buf1  = (unsigned long long*)(ws + OFF_BUF1);
  unsigned long long* buf2  = (unsigned long long*)(ws + OFF_BUF2);
  int* sel                  = (int*)(ws + OFF_SEL);
  int* keep                 = (int*)(ws + OFF_KEEP);

  // pad keys (anchors 36864..65535) and buf1 (chunks 9..15) with worst key
  hipMemsetAsync(ws + OFF_KEYS, 0xFF, 4194304ull + 1048576ull, stream);

  conv_mfma_kernel<<<dim3(8, 32, 8), dim3(256), 0, stream>>>(fm, base_w, base_b, x);
  heads_kernel<<<dim3(512), dim3(64, 4), 0, stream>>>(
      x, cls_w, cls_b, reg_w, reg_b, img_h, img_w, scores, boxes, keys);
  // exact top-1000: chunk sorts (top-1024 each) -> 2-level merge
  sort_topk_kernel<<<dim3(9, 8), dim3(1024), 0, stream>>>(keys, buf1, 65536, 16384);
  sort_topk_kernel<<<dim3(4, 8), dim3(1024), 0, stream>>>(buf1, buf2, 16384, 4096);
  sort_final_kernel<<<dim3(8), dim3(1024), 0, stream>>>(buf2, sel);
  nms_kernel<<<dim3(8), dim3(256), 0, stream>>>(boxes, sel, keep);
  out_kernel<<<dim3(8), dim3(1024), 0, stream>>>(boxes, scores, sel, keep, out);
}

// Round 5
// 3162.829 us; speedup vs baseline: 1.8255x; 1.2427x over previous
//
#include <hip/hip_runtime.h>
#include <math.h>

// RPNHead: conv3x3(512->512)+ReLU -> cls(9)/reg(36) 1x1 -> sigmoid/box-decode
// -> per-image exact top-1000 (by f64 score, index tie-break) -> greedy NMS
// -> [8,300,5] f32 output (kept-first stable order, zero-padded).
//
// Score/box pipeline in fp64 so top-k ordering and NMS decisions match a
// float64 numpy reference exactly (adjacent-score spacing ~5e-5..5e-8 >> f64
// noise ~1e-16; f32 would swap ranks -> wrong rows -> absmax ~1000).
//
// R2: conv as implicit-GEMM on v_mfma_f64_16x16x4_f64 (matrix pipe).
// R3: fixed weight-staging double-offset bug.
// R4: probe-decoded C/D layout (f64 MFMA mapping differs from CDNA2 docs).
//     PASSED, conv 3.44ms, MfmaUtil 61%, bank-conflict 1.17e8, occ 24%.
// R5: feed the matrix pipe: f32 LDS (+cvt_f64_f32 on read, halves LDS +
//     conflicts), sW stride 80 (2-way max = free), sIn strides 80/320,
//     double-buffered LDS with T14 split (loads issued before compute,
//     ds_write after -> ONE barrier/chunk, latency hidden), all staging
//     and fragment address algebra hoisted out of the K-loop.

typedef double f64x4 __attribute__((ext_vector_type(4)));

#define BS 8
#define CIN 512
#define COUT 512
#define FH 64
#define FW 64
#define NA 9
#define NPIX (FH*FW)          // 4096
#define NANCH (NPIX*NA)       // 36864
#define NPAD 65536
#define KPRE 1000
#define KPOST 300

// ---- workspace layout (bytes) ----
#define OFF_X      0ull                                   // 8*512*4096 f64 = 134217728
#define OFF_SCORES (OFF_X + 134217728ull)                 // 8*36864 f64    = 2359296
#define OFF_BOXES  (OFF_SCORES + 2359296ull)              // 8*36864*4 f64  = 9437184
#define OFF_KEYS   (OFF_BOXES + 9437184ull)               // 8*65536 u64    = 4194304
#define OFF_BUF1   (OFF_KEYS + 4194304ull)                // 8*16*1024 u64  = 1048576
#define OFF_BUF2   (OFF_BUF1 + 1048576ull)                // 8*4*1024 u64   = 262144
#define OFF_SEL    (OFF_BUF2 + 262144ull)                 // 8*1024 i32     = 32768
#define OFF_KEEP   (OFF_SEL + 32768ull)                   // 8*1024 i32     = 32768
#define WS_NEEDED  (OFF_KEEP + 32768ull)

// LDS geometry (f32 words): sW region [36][80], sIn region [4c][4r][80]
#define SW_STRIDE 80
#define SW_WORDS  (36 * SW_STRIDE)        // 2880
#define SI_RSTRIDE 80
#define SI_CSTRIDE 320
#define SI_WORDS  (4 * SI_CSTRIDE)        // 1280
#define BUF_WORDS (SW_WORDS + SI_WORDS)   // 4160

// ---------------- conv 3x3 + bias + relu, f64 MFMA implicit GEMM -------------
// grid (8 ocb, 32 rowpair, 8 b), block 256 = 4 waves, wave grid 2M x 2N.
// Block tile: 64 oc x 128 pix (2 image rows). Wave tile: 32 oc x 64 pix
// = 2x4 MFMA 16x16 tiles. K-chunk = 4 cin x 9 taps = 36, 128 chunks.
// Feed: A[m][k]: m=lane%16 (+16 per a1), k=lane/16. B[k][n]: k=lane/16,
// n=lane%16 (+16 per tn). D mapping decoded at runtime by probe (R4).
__device__ __forceinline__ void conv_compute(
    const float* __restrict__ sWp, const float* __restrict__ sIp,
    const int* __restrict__ boff, f64x4 acc[2][4]) {
#pragma unroll
  for (int k0s = 0; k0s < 9; ++k0s) {
    double a0 = (double)sWp[k0s * 4 * SW_STRIDE];
    double a1 = (double)sWp[k0s * 4 * SW_STRIDE + 16];
    const float* bp = sIp + boff[k0s];
    double b0 = (double)bp[0];
    double b1 = (double)bp[16];
    double b2 = (double)bp[32];
    double b3 = (double)bp[48];
    acc[0][0] = __builtin_amdgcn_mfma_f64_16x16x4f64(a0, b0, acc[0][0], 0, 0, 0);
    acc[0][1] = __builtin_amdgcn_mfma_f64_16x16x4f64(a0, b1, acc[0][1], 0, 0, 0);
    acc[0][2] = __builtin_amdgcn_mfma_f64_16x16x4f64(a0, b2, acc[0][2], 0, 0, 0);
    acc[0][3] = __builtin_amdgcn_mfma_f64_16x16x4f64(a0, b3, acc[0][3], 0, 0, 0);
    acc[1][0] = __builtin_amdgcn_mfma_f64_16x16x4f64(a1, b0, acc[1][0], 0, 0, 0);
    acc[1][1] = __builtin_amdgcn_mfma_f64_16x16x4f64(a1, b1, acc[1][1], 0, 0, 0);
    acc[1][2] = __builtin_amdgcn_mfma_f64_16x16x4f64(a1, b2, acc[1][2], 0, 0, 0);
    acc[1][3] = __builtin_amdgcn_mfma_f64_16x16x4f64(a1, b3, acc[1][3], 0, 0, 0);
  }
}

__global__ __launch_bounds__(256) void conv_mfma_kernel(
    const float* __restrict__ fm, const float* __restrict__ W,
    const float* __restrict__ bias, double* __restrict__ x) {
  __shared__ float sbuf[2 * BUF_WORDS];   // 33.3 KB, double-buffered
  const int ocb = blockIdx.x, rp = blockIdx.y, b = blockIdx.z;
  const int h0 = rp * 2;
  const int oc0 = ocb * 64;
  const int tid = threadIdx.x;
  const int wid = tid >> 6, l = tid & 63;
  const int q = l >> 4, r16 = l & 15;
  const int wm = wid >> 1, wn = wid & 1;   // wave grid 2(M) x 2(N)

  // ---- loop-invariant staging setup ----
  // weights: thread (wo=tid/4, wseg=tid%4) owns k = wseg*9+j, j=0..8
  const int wo = tid >> 2, wseg = tid & 3;
  const float* wbase = W + (size_t)(oc0 + wo) * 4608 + wseg * 9;
  const int wlds0 = (wseg * 9) * SW_STRIDE + wo;   // + j*SW_STRIDE

  // input: slot s covers li = tid + 256*s of [4c][4r][66col]
  const float* ibase[5];
  int idls[5];
  bool sact[5], lact[5];
#pragma unroll
  for (int s = 0; s < 5; ++s) {
    int li = tid + 256 * s;
    sact[s] = li < 1056;
    int li_c = sact[s] ? li : 0;
    int c = li_c / 264, rem = li_c % 264, r = rem / 66, col = rem % 66;
    int gy = h0 - 1 + r, gx = col - 1;
    lact[s] = sact[s] && gy >= 0 && gy < FH && gx >= 0 && gx < FW;
    ibase[s] = fm + (size_t)(b * CIN + c) * NPIX + gy * FW + gx;
    idls[s] = SW_WORDS + c * SI_CSTRIDE + r * SI_RSTRIDE + col;
  }

  // fragment read offsets (loop-invariant)
  const int apos = q * SW_STRIDE + wm * 32 + r16;
  const int ipos = SW_WORDS + wn * SI_RSTRIDE + r16;
  int boff[9];
#pragma unroll
  for (int k0s = 0; k0s < 9; ++k0s) {
    int k = k0s * 4 + q;
    int c = k / 9, t = k - 9 * c;
    int dy = t / 3, dx = t - 3 * dy;
    boff[k0s] = c * SI_CSTRIDE + dy * SI_RSTRIDE + dx;
  }

  f64x4 acc[2][4];
#pragma unroll
  for (int tm = 0; tm < 2; ++tm)
#pragma unroll
    for (int tn = 0; tn < 4; ++tn)
#pragma unroll
      for (int v = 0; v < 4; ++v) acc[tm][tn][v] = 0.0;

  float wreg[9], ireg[5];

#define LOAD_REGS(t) do {                                            \
    const int cc_ = 4 * (t);                                         \
    _Pragma("unroll")                                                \
    for (int j = 0; j < 9; ++j) wreg[j] = wbase[cc_ * 9 + j];        \
    _Pragma("unroll")                                                \
    for (int s = 0; s < 5; ++s)                                      \
      ireg[s] = lact[s] ? ibase[s][(size_t)cc_ * NPIX] : 0.f;        \
  } while (0)

#define WRITE_LDS(base) do {                                         \
    _Pragma("unroll")                                                \
    for (int j = 0; j < 9; ++j) (base)[wlds0 + j * SW_STRIDE] = wreg[j]; \
    _Pragma("unroll")                                                \
    for (int s = 0; s < 5; ++s)                                      \
      if (sact[s]) (base)[idls[s]] = ireg[s];                        \
  } while (0)

  float* buf0 = sbuf;
  float* buf1 = sbuf + BUF_WORDS;

  // prologue: chunk 0 -> buf0
  LOAD_REGS(0);
  WRITE_LDS(buf0);
  __syncthreads();

  for (int tt = 0; tt < 64; ++tt) {
    const int t1 = 2 * tt + 1;
    LOAD_REGS(t1);                       // in flight during compute
    conv_compute(buf0 + apos, buf0 + ipos, boff, acc);
    WRITE_LDS(buf1);
    __syncthreads();
    const int t2 = (t1 + 1 < 128) ? t1 + 1 : 127;   // dummy on last iter
    LOAD_REGS(t2);
    conv_compute(buf1 + apos, buf1 + ipos, boff, acc);
    WRITE_LDS(buf0);
    __syncthreads();
  }

  // ---- C/D layout probe (post-loop): D[i][j] = i + 16*j, exact ints.
  int prow[4], pcol[4];
  {
    f64x4 probe = {0.0, 0.0, 0.0, 0.0};
    double pa = (q == 0) ? (double)r16 : ((q == 1) ? 1.0 : 0.0);
    double pb = (q == 0) ? 1.0 : ((q == 1) ? (double)(16 * r16) : 0.0);
    probe = __builtin_amdgcn_mfma_f64_16x16x4f64(pa, pb, probe, 0, 0, 0);
#pragma unroll
    for (int v = 0; v < 4; ++v) {
      int val = (int)(probe[v] + 0.5);
      prow[v] = val & 15;
      pcol[v] = (val >> 4) & 15;
    }
  }

  // epilogue: probe-decoded D mapping; bias + relu
#pragma unroll
  for (int tm = 0; tm < 2; ++tm) {
#pragma unroll
    for (int v = 0; v < 4; ++v) {
      const int oc = oc0 + wm * 32 + tm * 16 + prow[v];
      const double bv = (double)bias[oc];
      const int h = h0 + wn;
#pragma unroll
      for (int tn = 0; tn < 4; ++tn) {
        const int w = tn * 16 + pcol[v];
        double val = acc[tm][tn][v] + bv;
        val = val > 0.0 ? val : 0.0;
        x[(size_t)(b * COUT + oc) * NPIX + h * FW + w] = val;
      }
    }
  }
#undef LOAD_REGS
#undef WRITE_LDS
}

// ---------------- heads: 45 logits/pixel -> scores, boxes, sort keys ----------
// grid 512 (= 8 img * 64 pixel-tiles of 64), block (64,4).
__global__ __launch_bounds__(256) void heads_kernel(
    const double* __restrict__ x, const float* __restrict__ cls_w,
    const float* __restrict__ cls_b, const float* __restrict__ reg_w,
    const float* __restrict__ reg_b, const int* __restrict__ img_h,
    const int* __restrict__ img_w, double* __restrict__ scores,
    double* __restrict__ boxes, unsigned long long* __restrict__ keys) {
  __shared__ double sx[4096];  // [ci][px]
  __shared__ double swl[2880]; // union: weights [45][64] per chunk, then logits [45][64]
  const int b = blockIdx.x >> 6;
  const int ptile = blockIdx.x & 63;
  const int tx = threadIdx.x, ty = threadIdx.y;
  const int tid = ty * 64 + tx;

  double acc[12];
#pragma unroll
  for (int j = 0; j < 12; ++j) acc[j] = 0.0;

  for (int cc = 0; cc < CIN; cc += 64) {
    for (int li = tid; li < 4096; li += 256) {
      int ci = li >> 6, px = li & 63;
      sx[li] = x[((long)b * CIN + cc + ci) * NPIX + ptile * 64 + px];
    }
    for (int li = tid; li < 2880; li += 256) {
      int o = li >> 6, ci = li & 63;
      float wv = (o < 9) ? cls_w[o * CIN + cc + ci] : reg_w[(o - 9) * CIN + cc + ci];
      swl[li] = (double)wv;
    }
    __syncthreads();
#pragma unroll 4
    for (int ci = 0; ci < 64; ++ci) {
      double xv = sx[ci * 64 + tx];
#pragma unroll
      for (int j = 0; j < 12; ++j) {
        int o = ty + 4 * j;
        if (o < 45) acc[j] += swl[o * 64 + ci] * xv;
      }
    }
    __syncthreads();
  }

  // bias, write logits to LDS (reuse swl)
#pragma unroll
  for (int j = 0; j < 12; ++j) {
    int o = ty + 4 * j;
    if (o < 45) {
      double bv = (o < 9) ? (double)cls_b[o] : (double)reg_b[o - 9];
      swl[o * 64 + tx] = acc[j] + bv;
    }
  }
  __syncthreads();

  const double ih = (double)img_h[0], iw = (double)img_w[0];
  const double sth = ih / (double)FH, stw = iw / (double)FW;
  const double ratios[3] = {0.5, 1.0, 2.0};
  const double sizes[3] = {128.0, 256.0, 512.0};

  for (int it = tid; it < 576; it += 256) {
    int px = it / 9, a = it % 9;
    int p = ptile * 64 + px;
    int hh = p >> 6, ww = p & 63;
    double z = swl[a * 64 + px];
    double score = 1.0 / (1.0 + exp(-z));
    double d0 = swl[(9 + a * 4 + 0) * 64 + px];
    double d1 = swl[(9 + a * 4 + 1) * 64 + px];
    double d2 = swl[(9 + a * 4 + 2) * 64 + px];
    double d3 = swl[(9 + a * 4 + 3) * 64 + px];
    double ratio = ratios[a / 3], size = sizes[a % 3];
    double hr = sqrt(ratio), wr = 1.0 / hr;
    double wsz = wr * size, hsz = hr * size;
    double sxc = (double)ww * stw, syc = (double)hh * sth;
    double ax0 = sxc - wsz * 0.5, ax1 = sxc + wsz * 0.5;
    double ay0 = syc - hsz * 0.5, ay1 = syc + hsz * 0.5;
    double aw = ax1 - ax0, ah = ay1 - ay0;
    double acx = ax0 + 0.5 * aw, acy = ay0 + 0.5 * ah;
    double pcx = d0 * aw + acx, pcy = d1 * ah + acy;
    double pw = exp(d2) * aw, ph = exp(d3) * ah;
    double bx0 = pcx - 0.5 * pw, by0 = pcy - 0.5 * ph;
    double bx1 = pcx + 0.5 * pw, by1 = pcy + 0.5 * ph;
    bx0 = fmin(fmax(bx0, 0.0), iw); bx1 = fmin(fmax(bx1, 0.0), iw);
    by0 = fmin(fmax(by0, 0.0), ih); by1 = fmin(fmax(by1, 0.0), ih);
    long n = (long)p * 9 + a;
    long base = (long)b * NANCH + n;
    boxes[base * 4 + 0] = bx0; boxes[base * 4 + 1] = by0;
    boxes[base * 4 + 2] = bx1; boxes[base * 4 + 3] = by1;
    scores[base] = score;
    // key: ascending-sortable, primary = descending score (48-bit truncated
    // bits of positive double), secondary = ascending index. n = ikey & 0xFFFF.
    unsigned long long bits = (unsigned long long)__double_as_longlong(score);
    keys[(long)b * NPAD + n] =
        ~((bits & 0xFFFFFFFFFFFF0000ull) | (0xFFFFull - (unsigned long long)n));
  }
}

// ---------------- bitonic sort of 4096 u64 in LDS (ascending) ----------------
__device__ inline void bitonic4096(unsigned long long* s, int tid) {
  for (int k = 2; k <= 4096; k <<= 1) {
    for (int j = k >> 1; j > 0; j >>= 1) {
#pragma unroll 2
      for (int t = tid; t < 2048; t += 1024) {
        int i = ((t & ~(j - 1)) << 1) | (t & (j - 1));
        int p = i | j;
        bool up = ((i & k) == 0);
        unsigned long long a = s[i], c = s[p];
        if ((a > c) == up) { s[i] = c; s[p] = a; }
      }
      __syncthreads();
    }
  }
}

// sorts a 4096 chunk, writes its smallest (best) 1024 keys.
__global__ __launch_bounds__(1024) void sort_topk_kernel(
    const unsigned long long* __restrict__ in, unsigned long long* __restrict__ out,
    long in_stride, long out_stride) {
  __shared__ unsigned long long s[4096];
  const int b = blockIdx.y, q = blockIdx.x, tid = threadIdx.x;
  const unsigned long long* ip = in + (long)b * in_stride + (long)q * 4096;
#pragma unroll 4
  for (int l = tid; l < 4096; l += 1024) s[l] = ip[l];
  __syncthreads();
  bitonic4096(s, tid);
  unsigned long long* op = out + (long)b * out_stride + (long)q * 1024;
  op[tid] = s[tid];
}

// final: sort 4096 candidates, decode top-1000 anchor indices.
__global__ __launch_bounds__(1024) void sort_final_kernel(
    const unsigned long long* __restrict__ in, int* __restrict__ sel) {
  __shared__ unsigned long long s[4096];
  const int b = blockIdx.x, tid = threadIdx.x;
  const unsigned long long* ip = in + (long)b * 4096;
#pragma unroll 4
  for (int l = tid; l < 4096; l += 1024) s[l] = ip[l];
  __syncthreads();
  bitonic4096(s, tid);
  if (tid < KPRE) sel[b * 1024 + tid] = (int)(s[tid] & 0xFFFFull);
}

// ---------------- greedy sequential NMS, f64, one block per image ------------
__global__ __launch_bounds__(256) void nms_kernel(
    const double* __restrict__ boxes, const int* __restrict__ sel,
    int* __restrict__ keep) {
  __shared__ double X0[KPRE], Y0[KPRE], X1[KPRE], Y1[KPRE], AR[KPRE];
  __shared__ int KP[KPRE];
  const int b = blockIdx.x, tid = threadIdx.x;
  for (int r = tid; r < KPRE; r += 256) {
    int n = sel[b * 1024 + r];
    const double* bp = boxes + ((long)b * NANCH + n) * 4;
    double x0 = bp[0], y0 = bp[1], x1 = bp[2], y1 = bp[3];
    X0[r] = x0; Y0[r] = y0; X1[r] = x1; Y1[r] = y1;
    AR[r] = (x1 - x0) * (y1 - y0);
    KP[r] = 1;
  }
  __syncthreads();
  for (int i = 0; i < KPRE - 1; ++i) {
    if (KP[i]) {
      double xi0 = X0[i], yi0 = Y0[i], xi1 = X1[i], yi1 = Y1[i], ai = AR[i];
      for (int j = i + 1 + tid; j < KPRE; j += 256) {
        double lx = fmax(xi0, X0[j]), ly = fmax(yi0, Y0[j]);
        double rx = fmin(xi1, X1[j]), ry = fmin(yi1, Y1[j]);
        double w = rx - lx; w = fmax(w, 0.0);
        double h = ry - ly; h = fmax(h, 0.0);
        double inter = w * h;
        double iou = inter / (ai + AR[j] - inter + 1e-9);
        if (iou > 0.7) KP[j] = 0;
      }
    }
    __syncthreads();
  }
  for (int r = tid; r < KPRE; r += 256) keep[b * 1024 + r] = KP[r];
}

// ---------------- output: kept-first stable order, zero pad ------------------
__global__ __launch_bounds__(1024) void out_kernel(
    const double* __restrict__ boxes, const double* __restrict__ scores,
    const int* __restrict__ sel, const int* __restrict__ keep,
    float* __restrict__ out) {
  const int b = blockIdx.x, tid = threadIdx.x;
  int kv = (tid < KPRE) ? keep[b * 1024 + tid] : 0;
  unsigned long long m = __ballot(kv != 0);
  int lane = tid & 63, wid = tid >> 6;
  __shared__ int wcnt[16], woff[16], tot;
  if (lane == 0) wcnt[wid] = __popcll(m);
  __syncthreads();
  if (tid == 0) {
    int s = 0;
    for (int w2 = 0; w2 < 16; ++w2) { woff[w2] = s; s += wcnt[w2]; }
    tot = s;
  }
  __syncthreads();
  int before = __popcll(m & ((1ull << lane) - 1ull));
  int pref = woff[wid] + before;  // kept strictly before tid
  if (tid < KPRE) {
    int pos = kv ? pref : (tot + (tid - pref));
    if (pos < KPOST) {
      float* o = out + ((long)b * KPOST + pos) * 5;
      if (kv) {
        int n = sel[b * 1024 + tid];
        const double* bp = boxes + ((long)b * NANCH + n) * 4;
        o[0] = (float)bp[0]; o[1] = (float)bp[1];
        o[2] = (float)bp[2]; o[3] = (float)bp[3];
        o[4] = (float)scores[(long)b * NANCH + n];
      } else {
        o[0] = 0.f; o[1] = 0.f; o[2] = 0.f; o[3] = 0.f; o[4] = 0.f;
      }
    }
  }
}

extern "C" void kernel_launch(void* const* d_in, const int* in_sizes, int n_in,
                              void* d_out, int out_size, void* d_ws, size_t ws_size,
                              hipStream_t stream) {
  const float* fm     = (const float*)d_in[0];
  const float* base_w = (const float*)d_in[1];
  const float* base_b = (const float*)d_in[2];
  const float* cls_w  = (const float*)d_in[3];
  const float* cls_b  = (const float*)d_in[4];
  const float* reg_w  = (const float*)d_in[5];
  const float* reg_b  = (const float*)d_in[6];
  const int* img_h    = (const int*)d_in[7];
  const int* img_w    = (const int*)d_in[8];
  float* out          = (float*)d_out;

  if (ws_size < WS_NEEDED) return;  // visible failure rather than corruption

  char* ws = (char*)d_ws;
  double* x                 = (double*)(ws + OFF_X);
  double* scores            = (double*)(ws + OFF_SCORES);
  double* boxes             = (double*)(ws + OFF_BOXES);
  unsigned long long* keys  = (unsigned long long*)(ws + OFF_KEYS);
  unsigned long long* buf1  = (unsigned long long*)(ws + OFF_BUF1);
  unsigned long long* buf2  = (unsigned long long*)(ws + OFF_BUF2);
  int* sel                  = (int*)(ws + OFF_SEL);
  int* keep                 = (int*)(ws + OFF_KEEP);

  // pad keys (anchors 36864..65535) and buf1 (chunks 9..15) with worst key
  hipMemsetAsync(ws + OFF_KEYS, 0xFF, 4194304ull + 1048576ull, stream);

  conv_mfma_kernel<<<dim3(8, 32, 8), dim3(256), 0, stream>>>(fm, base_w, base_b, x);
  heads_kernel<<<dim3(512), dim3(64, 4), 0, stream>>>(
      x, cls_w, cls_b, reg_w, reg_b, img_h, img_w, scores, boxes, keys);
  // exact top-1000: chunk sorts (top-1024 each) -> 2-level merge
  sort_topk_kernel<<<dim3(9, 8), dim3(1024), 0, stream>>>(keys, buf1, 65536, 16384);
  sort_topk_kernel<<<dim3(4, 8), dim3(1024), 0, stream>>>(buf1, buf2, 16384, 4096);
  sort_final_kernel<<<dim3(8), dim3(1024), 0, stream>>>(buf2, sel);
  nms_kernel<<<dim3(8), dim3(256), 0, stream>>>(boxes, sel, keep);
  out_kernel<<<dim3(8), dim3(1024), 0, stream>>>(boxes, scores, sel, keep, out);
}

// Round 6
// 3058.167 us; speedup vs baseline: 1.8880x; 1.0342x over previous
//
#include <hip/hip_runtime.h>
#include <math.h>

// RPNHead: conv3x3(512->512)+ReLU -> cls(9)/reg(36) 1x1 -> sigmoid/box-decode
// -> per-image exact top-1000 (by f64 score, index tie-break) -> greedy NMS
// -> [8,300,5] f32 output (kept-first stable order, zero-padded).
//
// Score/box pipeline in fp64 so top-k ordering and NMS decisions match a
// float64 numpy reference exactly (adjacent-score spacing ~5e-5..5e-8 >> f64
// noise ~1e-16; f32 would swap ranks -> wrong rows -> absmax ~1000).
//
// R2: conv as implicit-GEMM on v_mfma_f64_16x16x4_f64 (matrix pipe).
// R3: fixed weight-staging double-offset bug.
// R4: probe-decoded C/D layout (f64 MFMA mapping differs from CDNA2 docs).
// R5: f32 LDS + stride-80 pad + double-buffer w/ T14 split + hoisted
//     addressing. conv 2647us, MfmaUtil 81%, occ 23% (2 waves/SIMD,
//     176 unified regs/wave).
// R6: occupancy 2->3 waves/SIMD: compress input staging pointers (10 VGPR)
//     to base + int offsets (5), __launch_bounds__(256,3) caps regs at
//     ~170; s_setprio(1) around the MFMA cluster (T5; dbuf gives wave
//     role-split across co-resident blocks).

typedef double f64x4 __attribute__((ext_vector_type(4)));

#define BS 8
#define CIN 512
#define COUT 512
#define FH 64
#define FW 64
#define NA 9
#define NPIX (FH*FW)          // 4096
#define NANCH (NPIX*NA)       // 36864
#define NPAD 65536
#define KPRE 1000
#define KPOST 300

// ---- workspace layout (bytes) ----
#define OFF_X      0ull                                   // 8*512*4096 f64 = 134217728
#define OFF_SCORES (OFF_X + 134217728ull)                 // 8*36864 f64    = 2359296
#define OFF_BOXES  (OFF_SCORES + 2359296ull)              // 8*36864*4 f64  = 9437184
#define OFF_KEYS   (OFF_BOXES + 9437184ull)               // 8*65536 u64    = 4194304
#define OFF_BUF1   (OFF_KEYS + 4194304ull)                // 8*16*1024 u64  = 1048576
#define OFF_BUF2   (OFF_BUF1 + 1048576ull)                // 8*4*1024 u64   = 262144
#define OFF_SEL    (OFF_BUF2 + 262144ull)                 // 8*1024 i32     = 32768
#define OFF_KEEP   (OFF_SEL + 32768ull)                   // 8*1024 i32     = 32768
#define WS_NEEDED  (OFF_KEEP + 32768ull)

// LDS geometry (f32 words): sW region [36][80], sIn region [4c][4r][80]
#define SW_STRIDE 80
#define SW_WORDS  (36 * SW_STRIDE)        // 2880
#define SI_RSTRIDE 80
#define SI_CSTRIDE 320
#define SI_WORDS  (4 * SI_CSTRIDE)        // 1280
#define BUF_WORDS (SW_WORDS + SI_WORDS)   // 4160

// ---------------- conv 3x3 + bias + relu, f64 MFMA implicit GEMM -------------
// grid (8 ocb, 32 rowpair, 8 b), block 256 = 4 waves, wave grid 2M x 2N.
// Block tile: 64 oc x 128 pix (2 image rows). Wave tile: 32 oc x 64 pix
// = 2x4 MFMA 16x16 tiles. K-chunk = 4 cin x 9 taps = 36, 128 chunks.
// Feed: A[m][k]: m=lane%16 (+16 per a1), k=lane/16. B[k][n]: k=lane/16,
// n=lane%16 (+16 per tn). D mapping decoded at runtime by probe (R4).
__device__ __forceinline__ void conv_compute(
    const float* __restrict__ sWp, const float* __restrict__ sIp,
    const int* __restrict__ boff, f64x4 acc[2][4]) {
#pragma unroll
  for (int k0s = 0; k0s < 9; ++k0s) {
    double a0 = (double)sWp[k0s * 4 * SW_STRIDE];
    double a1 = (double)sWp[k0s * 4 * SW_STRIDE + 16];
    const float* bp = sIp + boff[k0s];
    double b0 = (double)bp[0];
    double b1 = (double)bp[16];
    double b2 = (double)bp[32];
    double b3 = (double)bp[48];
    acc[0][0] = __builtin_amdgcn_mfma_f64_16x16x4f64(a0, b0, acc[0][0], 0, 0, 0);
    acc[0][1] = __builtin_amdgcn_mfma_f64_16x16x4f64(a0, b1, acc[0][1], 0, 0, 0);
    acc[0][2] = __builtin_amdgcn_mfma_f64_16x16x4f64(a0, b2, acc[0][2], 0, 0, 0);
    acc[0][3] = __builtin_amdgcn_mfma_f64_16x16x4f64(a0, b3, acc[0][3], 0, 0, 0);
    acc[1][0] = __builtin_amdgcn_mfma_f64_16x16x4f64(a1, b0, acc[1][0], 0, 0, 0);
    acc[1][1] = __builtin_amdgcn_mfma_f64_16x16x4f64(a1, b1, acc[1][1], 0, 0, 0);
    acc[1][2] = __builtin_amdgcn_mfma_f64_16x16x4f64(a1, b2, acc[1][2], 0, 0, 0);
    acc[1][3] = __builtin_amdgcn_mfma_f64_16x16x4f64(a1, b3, acc[1][3], 0, 0, 0);
  }
}

__global__ __launch_bounds__(256, 3) void conv_mfma_kernel(
    const float* __restrict__ fm, const float* __restrict__ W,
    const float* __restrict__ bias, double* __restrict__ x) {
  __shared__ float sbuf[2 * BUF_WORDS];   // 33.3 KB, double-buffered
  const int ocb = blockIdx.x, rp = blockIdx.y, b = blockIdx.z;
  const int h0 = rp * 2;
  const int oc0 = ocb * 64;
  const int tid = threadIdx.x;
  const int wid = tid >> 6, l = tid & 63;
  const int q = l >> 4, r16 = l & 15;
  const int wm = wid >> 1, wn = wid & 1;   // wave grid 2(M) x 2(N)

  // ---- loop-invariant staging setup ----
  // weights: thread (wo=tid/4, wseg=tid%4) owns k = wseg*9+j, j=0..8
  const int wo = tid >> 2, wseg = tid & 3;
  const float* wbase = W + (size_t)(oc0 + wo) * 4608 + wseg * 9;
  const int wlds0 = (wseg * 9) * SW_STRIDE + wo;   // + j*SW_STRIDE

  // input: slot s covers li = tid + 256*s of [4c][4r][66col]
  // single base pointer + int offsets (reg-pressure: 5 ints vs 5 ptrs)
  const float* fmb = fm + (size_t)b * CIN * NPIX;
  int ioff[5];
  int idls[5];
  bool sact[5], lact[5];
#pragma unroll
  for (int s = 0; s < 5; ++s) {
    int li = tid + 256 * s;
    sact[s] = li < 1056;
    int li_c = sact[s] ? li : 0;
    int c = li_c / 264, rem = li_c % 264, r = rem / 66, col = rem % 66;
    int gy = h0 - 1 + r, gx = col - 1;
    lact[s] = sact[s] && gy >= 0 && gy < FH && gx >= 0 && gx < FW;
    ioff[s] = lact[s] ? (c * NPIX + gy * FW + gx) : 0;
    idls[s] = SW_WORDS + c * SI_CSTRIDE + r * SI_RSTRIDE + col;
  }

  // fragment read offsets (loop-invariant)
  const int apos = q * SW_STRIDE + wm * 32 + r16;
  const int ipos = SW_WORDS + wn * SI_RSTRIDE + r16;
  int boff[9];
#pragma unroll
  for (int k0s = 0; k0s < 9; ++k0s) {
    int k = k0s * 4 + q;
    int c = k / 9, t = k - 9 * c;
    int dy = t / 3, dx = t - 3 * dy;
    boff[k0s] = c * SI_CSTRIDE + dy * SI_RSTRIDE + dx;
  }

  f64x4 acc[2][4];
#pragma unroll
  for (int tm = 0; tm < 2; ++tm)
#pragma unroll
    for (int tn = 0; tn < 4; ++tn)
#pragma unroll
      for (int v = 0; v < 4; ++v) acc[tm][tn][v] = 0.0;

  float wreg[9], ireg[5];

#define LOAD_REGS(t) do {                                            \
    const int cc_ = 4 * (t);                                         \
    _Pragma("unroll")                                                \
    for (int j = 0; j < 9; ++j) wreg[j] = wbase[cc_ * 9 + j];        \
    _Pragma("unroll")                                                \
    for (int s = 0; s < 5; ++s)                                      \
      ireg[s] = lact[s] ? fmb[(size_t)(ioff[s] + cc_ * NPIX)] : 0.f; \
  } while (0)

#define WRITE_LDS(base) do {                                         \
    _Pragma("unroll")                                                \
    for (int j = 0; j < 9; ++j) (base)[wlds0 + j * SW_STRIDE] = wreg[j]; \
    _Pragma("unroll")                                                \
    for (int s = 0; s < 5; ++s)                                      \
      if (sact[s]) (base)[idls[s]] = ireg[s];                        \
  } while (0)

  float* buf0 = sbuf;
  float* buf1 = sbuf + BUF_WORDS;

  // prologue: chunk 0 -> buf0
  LOAD_REGS(0);
  WRITE_LDS(buf0);
  __syncthreads();

  for (int tt = 0; tt < 64; ++tt) {
    const int t1 = 2 * tt + 1;
    LOAD_REGS(t1);                       // in flight during compute
    __builtin_amdgcn_s_setprio(1);
    conv_compute(buf0 + apos, buf0 + ipos, boff, acc);
    __builtin_amdgcn_s_setprio(0);
    WRITE_LDS(buf1);
    __syncthreads();
    const int t2 = (t1 + 1 < 128) ? t1 + 1 : 127;   // dummy on last iter
    LOAD_REGS(t2);
    __builtin_amdgcn_s_setprio(1);
    conv_compute(buf1 + apos, buf1 + ipos, boff, acc);
    __builtin_amdgcn_s_setprio(0);
    WRITE_LDS(buf0);
    __syncthreads();
  }

  // ---- C/D layout probe (post-loop): D[i][j] = i + 16*j, exact ints.
  int prow[4], pcol[4];
  {
    f64x4 probe = {0.0, 0.0, 0.0, 0.0};
    double pa = (q == 0) ? (double)r16 : ((q == 1) ? 1.0 : 0.0);
    double pb = (q == 0) ? 1.0 : ((q == 1) ? (double)(16 * r16) : 0.0);
    probe = __builtin_amdgcn_mfma_f64_16x16x4f64(pa, pb, probe, 0, 0, 0);
#pragma unroll
    for (int v = 0; v < 4; ++v) {
      int val = (int)(probe[v] + 0.5);
      prow[v] = val & 15;
      pcol[v] = (val >> 4) & 15;
    }
  }

  // epilogue: probe-decoded D mapping; bias + relu
#pragma unroll
  for (int tm = 0; tm < 2; ++tm) {
#pragma unroll
    for (int v = 0; v < 4; ++v) {
      const int oc = oc0 + wm * 32 + tm * 16 + prow[v];
      const double bv = (double)bias[oc];
      const int h = h0 + wn;
#pragma unroll
      for (int tn = 0; tn < 4; ++tn) {
        const int w = tn * 16 + pcol[v];
        double val = acc[tm][tn][v] + bv;
        val = val > 0.0 ? val : 0.0;
        x[(size_t)(b * COUT + oc) * NPIX + h * FW + w] = val;
      }
    }
  }
#undef LOAD_REGS
#undef WRITE_LDS
}

// ---------------- heads: 45 logits/pixel -> scores, boxes, sort keys ----------
// grid 512 (= 8 img * 64 pixel-tiles of 64), block (64,4).
__global__ __launch_bounds__(256) void heads_kernel(
    const double* __restrict__ x, const float* __restrict__ cls_w,
    const float* __restrict__ cls_b, const float* __restrict__ reg_w,
    const float* __restrict__ reg_b, const int* __restrict__ img_h,
    const int* __restrict__ img_w, double* __restrict__ scores,
    double* __restrict__ boxes, unsigned long long* __restrict__ keys) {
  __shared__ double sx[4096];  // [ci][px]
  __shared__ double swl[2880]; // union: weights [45][64] per chunk, then logits [45][64]
  const int b = blockIdx.x >> 6;
  const int ptile = blockIdx.x & 63;
  const int tx = threadIdx.x, ty = threadIdx.y;
  const int tid = ty * 64 + tx;

  double acc[12];
#pragma unroll
  for (int j = 0; j < 12; ++j) acc[j] = 0.0;

  for (int cc = 0; cc < CIN; cc += 64) {
    for (int li = tid; li < 4096; li += 256) {
      int ci = li >> 6, px = li & 63;
      sx[li] = x[((long)b * CIN + cc + ci) * NPIX + ptile * 64 + px];
    }
    for (int li = tid; li < 2880; li += 256) {
      int o = li >> 6, ci = li & 63;
      float wv = (o < 9) ? cls_w[o * CIN + cc + ci] : reg_w[(o - 9) * CIN + cc + ci];
      swl[li] = (double)wv;
    }
    __syncthreads();
#pragma unroll 4
    for (int ci = 0; ci < 64; ++ci) {
      double xv = sx[ci * 64 + tx];
#pragma unroll
      for (int j = 0; j < 12; ++j) {
        int o = ty + 4 * j;
        if (o < 45) acc[j] += swl[o * 64 + ci] * xv;
      }
    }
    __syncthreads();
  }

  // bias, write logits to LDS (reuse swl)
#pragma unroll
  for (int j = 0; j < 12; ++j) {
    int o = ty + 4 * j;
    if (o < 45) {
      double bv = (o < 9) ? (double)cls_b[o] : (double)reg_b[o - 9];
      swl[o * 64 + tx] = acc[j] + bv;
    }
  }
  __syncthreads();

  const double ih = (double)img_h[0], iw = (double)img_w[0];
  const double sth = ih / (double)FH, stw = iw / (double)FW;
  const double ratios[3] = {0.5, 1.0, 2.0};
  const double sizes[3] = {128.0, 256.0, 512.0};

  for (int it = tid; it < 576; it += 256) {
    int px = it / 9, a = it % 9;
    int p = ptile * 64 + px;
    int hh = p >> 6, ww = p & 63;
    double z = swl[a * 64 + px];
    double score = 1.0 / (1.0 + exp(-z));
    double d0 = swl[(9 + a * 4 + 0) * 64 + px];
    double d1 = swl[(9 + a * 4 + 1) * 64 + px];
    double d2 = swl[(9 + a * 4 + 2) * 64 + px];
    double d3 = swl[(9 + a * 4 + 3) * 64 + px];
    double ratio = ratios[a / 3], size = sizes[a % 3];
    double hr = sqrt(ratio), wr = 1.0 / hr;
    double wsz = wr * size, hsz = hr * size;
    double sxc = (double)ww * stw, syc = (double)hh * sth;
    double ax0 = sxc - wsz * 0.5, ax1 = sxc + wsz * 0.5;
    double ay0 = syc - hsz * 0.5, ay1 = syc + hsz * 0.5;
    double aw = ax1 - ax0, ah = ay1 - ay0;
    double acx = ax0 + 0.5 * aw, acy = ay0 + 0.5 * ah;
    double pcx = d0 * aw + acx, pcy = d1 * ah + acy;
    double pw = exp(d2) * aw, ph = exp(d3) * ah;
    double bx0 = pcx - 0.5 * pw, by0 = pcy - 0.5 * ph;
    double bx1 = pcx + 0.5 * pw, by1 = pcy + 0.5 * ph;
    bx0 = fmin(fmax(bx0, 0.0), iw); bx1 = fmin(fmax(bx1, 0.0), iw);
    by0 = fmin(fmax(by0, 0.0), ih); by1 = fmin(fmax(by1, 0.0), ih);
    long n = (long)p * 9 + a;
    long base = (long)b * NANCH + n;
    boxes[base * 4 + 0] = bx0; boxes[base * 4 + 1] = by0;
    boxes[base * 4 + 2] = bx1; boxes[base * 4 + 3] = by1;
    scores[base] = score;
    // key: ascending-sortable, primary = descending score (48-bit truncated
    // bits of positive double), secondary = ascending index. n = ikey & 0xFFFF.
    unsigned long long bits = (unsigned long long)__double_as_longlong(score);
    keys[(long)b * NPAD + n] =
        ~((bits & 0xFFFFFFFFFFFF0000ull) | (0xFFFFull - (unsigned long long)n));
  }
}

// ---------------- bitonic sort of 4096 u64 in LDS (ascending) ----------------
__device__ inline void bitonic4096(unsigned long long* s, int tid) {
  for (int k = 2; k <= 4096; k <<= 1) {
    for (int j = k >> 1; j > 0; j >>= 1) {
#pragma unroll 2
      for (int t = tid; t < 2048; t += 1024) {
        int i = ((t & ~(j - 1)) << 1) | (t & (j - 1));
        int p = i | j;
        bool up = ((i & k) == 0);
        unsigned long long a = s[i], c = s[p];
        if ((a > c) == up) { s[i] = c; s[p] = a; }
      }
      __syncthreads();
    }
  }
}

// sorts a 4096 chunk, writes its smallest (best) 1024 keys.
__global__ __launch_bounds__(1024) void sort_topk_kernel(
    const unsigned long long* __restrict__ in, unsigned long long* __restrict__ out,
    long in_stride, long out_stride) {
  __shared__ unsigned long long s[4096];
  const int b = blockIdx.y, q = blockIdx.x, tid = threadIdx.x;
  const unsigned long long* ip = in + (long)b * in_stride + (long)q * 4096;
#pragma unroll 4
  for (int l = tid; l < 4096; l += 1024) s[l] = ip[l];
  __syncthreads();
  bitonic4096(s, tid);
  unsigned long long* op = out + (long)b * out_stride + (long)q * 1024;
  op[tid] = s[tid];
}

// final: sort 4096 candidates, decode top-1000 anchor indices.
__global__ __launch_bounds__(1024) void sort_final_kernel(
    const unsigned long long* __restrict__ in, int* __restrict__ sel) {
  __shared__ unsigned long long s[4096];
  const int b = blockIdx.x, tid = threadIdx.x;
  const unsigned long long* ip = in + (long)b * 4096;
#pragma unroll 4
  for (int l = tid; l < 4096; l += 1024) s[l] = ip[l];
  __syncthreads();
  bitonic4096(s, tid);
  if (tid < KPRE) sel[b * 1024 + tid] = (int)(s[tid] & 0xFFFFull);
}

// ---------------- greedy sequential NMS, f64, one block per image ------------
__global__ __launch_bounds__(256) void nms_kernel(
    const double* __restrict__ boxes, const int* __restrict__ sel,
    int* __restrict__ keep) {
  __shared__ double X0[KPRE], Y0[KPRE], X1[KPRE], Y1[KPRE], AR[KPRE];
  __shared__ int KP[KPRE];
  const int b = blockIdx.x, tid = threadIdx.x;
  for (int r = tid; r < KPRE; r += 256) {
    int n = sel[b * 1024 + r];
    const double* bp = boxes + ((long)b * NANCH + n) * 4;
    double x0 = bp[0], y0 = bp[1], x1 = bp[2], y1 = bp[3];
    X0[r] = x0; Y0[r] = y0; X1[r] = x1; Y1[r] = y1;
    AR[r] = (x1 - x0) * (y1 - y0);
    KP[r] = 1;
  }
  __syncthreads();
  for (int i = 0; i < KPRE - 1; ++i) {
    if (KP[i]) {
      double xi0 = X0[i], yi0 = Y0[i], xi1 = X1[i], yi1 = Y1[i], ai = AR[i];
      for (int j = i + 1 + tid; j < KPRE; j += 256) {
        double lx = fmax(xi0, X0[j]), ly = fmax(yi0, Y0[j]);
        double rx = fmin(xi1, X1[j]), ry = fmin(yi1, Y1[j]);
        double w = rx - lx; w = fmax(w, 0.0);
        double h = ry - ly; h = fmax(h, 0.0);
        double inter = w * h;
        double iou = inter / (ai + AR[j] - inter + 1e-9);
        if (iou > 0.7) KP[j] = 0;
      }
    }
    __syncthreads();
  }
  for (int r = tid; r < KPRE; r += 256) keep[b * 1024 + r] = KP[r];
}

// ---------------- output: kept-first stable order, zero pad ------------------
__global__ __launch_bounds__(1024) void out_kernel(
    const double* __restrict__ boxes, const double* __restrict__ scores,
    const int* __restrict__ sel, const int* __restrict__ keep,
    float* __restrict__ out) {
  const int b = blockIdx.x, tid = threadIdx.x;
  int kv = (tid < KPRE) ? keep[b * 1024 + tid] : 0;
  unsigned long long m = __ballot(kv != 0);
  int lane = tid & 63, wid = tid >> 6;
  __shared__ int wcnt[16], woff[16], tot;
  if (lane == 0) wcnt[wid] = __popcll(m);
  __syncthreads();
  if (tid == 0) {
    int s = 0;
    for (int w2 = 0; w2 < 16; ++w2) { woff[w2] = s; s += wcnt[w2]; }
    tot = s;
  }
  __syncthreads();
  int before = __popcll(m & ((1ull << lane) - 1ull));
  int pref = woff[wid] + before;  // kept strictly before tid
  if (tid < KPRE) {
    int pos = kv ? pref : (tot + (tid - pref));
    if (pos < KPOST) {
      float* o = out + ((long)b * KPOST + pos) * 5;
      if (kv) {
        int n = sel[b * 1024 + tid];
        const double* bp = boxes + ((long)b * NANCH + n) * 4;
        o[0] = (float)bp[0]; o[1] = (float)bp[1];
        o[2] = (float)bp[2]; o[3] = (float)bp[3];
        o[4] = (float)scores[(long)b * NANCH + n];
      } else {
        o[0] = 0.f; o[1] = 0.f; o[2] = 0.f; o[3] = 0.f; o[4] = 0.f;
      }
    }
  }
}

extern "C" void kernel_launch(void* const* d_in, const int* in_sizes, int n_in,
                              void* d_out, int out_size, void* d_ws, size_t ws_size,
                              hipStream_t stream) {
  const float* fm     = (const float*)d_in[0];
  const float* base_w = (const float*)d_in[1];
  const float* base_b = (const float*)d_in[2];
  const float* cls_w  = (const float*)d_in[3];
  const float* cls_b  = (const float*)d_in[4];
  const float* reg_w  = (const float*)d_in[5];
  const float* reg_b  = (const float*)d_in[6];
  const int* img_h    = (const int*)d_in[7];
  const int* img_w    = (const int*)d_in[8];
  float* out          = (float*)d_out;

  if (ws_size < WS_NEEDED) return;  // visible failure rather than corruption

  char* ws = (char*)d_ws;
  double* x                 = (double*)(ws + OFF_X);
  double* scores            = (double*)(ws + OFF_SCORES);
  double* boxes             = (double*)(ws + OFF_BOXES);
  unsigned long long* keys  = (unsigned long long*)(ws + OFF_KEYS);
  unsigned long long* buf1  = (unsigned long long*)(ws + OFF_BUF1);
  unsigned long long* buf2  = (unsigned long long*)(ws + OFF_BUF2);
  int* sel                  = (int*)(ws + OFF_SEL);
  int* keep                 = (int*)(ws + OFF_KEEP);

  // pad keys (anchors 36864..65535) and buf1 (chunks 9..15) with worst key
  hipMemsetAsync(ws + OFF_KEYS, 0xFF, 4194304ull + 1048576ull, stream);

  conv_mfma_kernel<<<dim3(8, 32, 8), dim3(256), 0, stream>>>(fm, base_w, base_b, x);
  heads_kernel<<<dim3(512), dim3(64, 4), 0, stream>>>(
      x, cls_w, cls_b, reg_w, reg_b, img_h, img_w, scores, boxes, keys);
  // exact top-1000: chunk sorts (top-1024 each) -> 2-level merge
  sort_topk_kernel<<<dim3(9, 8), dim3(1024), 0, stream>>>(keys, buf1, 65536, 16384);
  sort_topk_kernel<<<dim3(4, 8), dim3(1024), 0, stream>>>(buf1, buf2, 16384, 4096);
  sort_final_kernel<<<dim3(8), dim3(1024), 0, stream>>>(buf2, sel);
  nms_kernel<<<dim3(8), dim3(256), 0, stream>>>(boxes, sel, keep);
  out_kernel<<<dim3(8), dim3(1024), 0, stream>>>(boxes, scores, sel, keep, out);
}